// Round 1
// baseline (365.796 us; speedup 1.0000x reference)
//
#include <hip/hip_runtime.h>
#include <math.h>

namespace {

constexpr int D   = 40;     // n_embed
constexpr int HS  = 10;     // head size
constexpr int NH  = 4;      // heads
constexpr int TT  = 2048;   // seq len
constexpr int BB  = 16;     // batch
constexpr int ROWS = BB * TT;       // 32768
constexpr int JT  = 256;            // attention j-tile

// ---------------- Kernel 1: LN1 + QKV projection ----------------
__global__ __launch_bounds__(128) void k_ln_qkv(
    const float* __restrict__ x,  const float* __restrict__ Wq,
    const float* __restrict__ Wk, const float* __restrict__ Wv,
    const float* __restrict__ g1, const float* __restrict__ be1,
    float* __restrict__ xn, float* __restrict__ qo,
    float* __restrict__ ko, float* __restrict__ vo)
{
    __shared__ float wq_s[NH*D*HS], wk_s[NH*D*HS], wv_s[NH*D*HS];
    __shared__ float g_s[D], b_s[D];
    const int tid = threadIdx.x;
    for (int i = tid; i < NH*D*HS; i += 128) {
        wq_s[i] = Wq[i]; wk_s[i] = Wk[i]; wv_s[i] = Wv[i];
    }
    if (tid < D) { g_s[tid] = g1[tid]; b_s[tid] = be1[tid]; }
    __syncthreads();

    const int row = blockIdx.x * 128 + tid;
    float xr[D];
    const float4* xp = reinterpret_cast<const float4*>(x + (size_t)row * D);
    #pragma unroll
    for (int i = 0; i < D/4; ++i) {
        float4 t4 = xp[i];
        xr[4*i+0]=t4.x; xr[4*i+1]=t4.y; xr[4*i+2]=t4.z; xr[4*i+3]=t4.w;
    }
    float mu = 0.f;
    #pragma unroll
    for (int d = 0; d < D; ++d) mu += xr[d];
    mu *= (1.f/D);
    float var = 0.f;
    #pragma unroll
    for (int d = 0; d < D; ++d) { float dd = xr[d]-mu; var += dd*dd; }
    var *= (1.f/D);
    const float rs = rsqrtf(var + 1e-5f);
    #pragma unroll
    for (int d = 0; d < D; ++d) xr[d] = (xr[d]-mu)*rs*g_s[d] + b_s[d];

    float4* xo = reinterpret_cast<float4*>(xn + (size_t)row * D);
    #pragma unroll
    for (int i = 0; i < D/4; ++i) {
        float4 t4; t4.x=xr[4*i+0]; t4.y=xr[4*i+1]; t4.z=xr[4*i+2]; t4.w=xr[4*i+3];
        xo[i] = t4;
    }

    const int b = row >> 11;          // row / 2048
    const int t = row & (TT-1);
    for (int h = 0; h < NH; ++h) {
        float aq[HS], ak[HS], av[HS];
        #pragma unroll
        for (int e = 0; e < HS; ++e) { aq[e]=0.f; ak[e]=0.f; av[e]=0.f; }
        const float* wq_p = &wq_s[h*D*HS];
        const float* wk_p = &wk_s[h*D*HS];
        const float* wv_p = &wv_s[h*D*HS];
        for (int d = 0; d < D; ++d) {
            const float xd = xr[d];
            #pragma unroll
            for (int e = 0; e < HS; ++e) {
                aq[e] = fmaf(xd, wq_p[d*HS+e], aq[e]);
                ak[e] = fmaf(xd, wk_p[d*HS+e], ak[e]);
                av[e] = fmaf(xd, wv_p[d*HS+e], av[e]);
            }
        }
        const size_t off = ((((size_t)b*NH + h)*TT) + t)*HS;
        #pragma unroll
        for (int e = 0; e < HS; e += 2) {
            *reinterpret_cast<float2*>(&qo[off+e]) = make_float2(aq[e], aq[e+1]);
            *reinterpret_cast<float2*>(&ko[off+e]) = make_float2(ak[e], ak[e+1]);
            *reinterpret_cast<float2*>(&vo[off+e]) = make_float2(av[e], av[e+1]);
        }
    }
}

// ---------------- Kernel 2: flash attention (scores = k_i . q_j) ----------------
__global__ __launch_bounds__(256) void k_attn(
    const float* __restrict__ q, const float* __restrict__ k,
    const float* __restrict__ v, float* __restrict__ o)
{
    __shared__ float qs[JT*HS], vs[JT*HS];
    const int bh   = blockIdx.x;   // 0..63  (b*NH + h)
    const int tile = blockIdx.y;   // 0..7
    const int tid  = threadIdx.x;
    const size_t base = (size_t)bh * TT * HS;
    const int i = tile * 256 + tid;

    float kr[HS];
    const float* kp = k + base + (size_t)i * HS;
    #pragma unroll
    for (int e = 0; e < HS; ++e) kr[e] = kp[e];

    float m = -1e30f, l = 0.f;
    float acc[HS];
    #pragma unroll
    for (int e = 0; e < HS; ++e) acc[e] = 0.f;

    for (int j0 = 0; j0 < TT; j0 += JT) {
        __syncthreads();
        for (int idx = tid; idx < JT*HS; idx += 256) {
            qs[idx] = q[base + (size_t)j0*HS + idx];
            vs[idx] = v[base + (size_t)j0*HS + idx];
        }
        __syncthreads();
        for (int jj = 0; jj < JT; ++jj) {
            const float* qp = &qs[jj*HS];
            float s = 0.f;
            #pragma unroll
            for (int e = 0; e < HS; ++e) s = fmaf(kr[e], qp[e], s);
            if (s > m) {                      // rare after warm-up
                const float c = __expf(m - s);
                l *= c;
                #pragma unroll
                for (int e = 0; e < HS; ++e) acc[e] *= c;
                m = s;
            }
            const float p = __expf(s - m);
            l += p;
            const float* vp = &vs[jj*HS];
            #pragma unroll
            for (int e = 0; e < HS; ++e) acc[e] = fmaf(p, vp[e], acc[e]);
        }
    }
    const float inv = 1.f / l;
    float* op = o + base + (size_t)i * HS;
    #pragma unroll
    for (int e = 0; e < HS; e += 2)
        *reinterpret_cast<float2*>(&op[e]) = make_float2(acc[e]*inv, acc[e+1]*inv);
}

// ---------------- Kernel 3: concat + proj + residual + LN2 + FFN + residual ----------------
__global__ __launch_bounds__(128) void k_epilogue(
    const float* __restrict__ attn, const float* __restrict__ xn,
    const float* __restrict__ Wp, const float* __restrict__ bp,
    const float* __restrict__ W1, const float* __restrict__ b1,
    const float* __restrict__ W2, const float* __restrict__ b2,
    const float* __restrict__ g2, const float* __restrict__ be2,
    float* __restrict__ out)
{
    __shared__ float wp_s[D*D], w1_s[D*D], w2_s[D*D];
    __shared__ float bp_s[D], b1_s[D], b2_s[D], g_s[D], be_s[D];
    const int tid = threadIdx.x;
    for (int i = tid; i < D*D; i += 128) { wp_s[i]=Wp[i]; w1_s[i]=W1[i]; w2_s[i]=W2[i]; }
    if (tid < D) {
        bp_s[tid]=bp[tid]; b1_s[tid]=b1[tid]; b2_s[tid]=b2[tid];
        g_s[tid]=g2[tid]; be_s[tid]=be2[tid];
    }
    __syncthreads();

    const int row = blockIdx.x * 128 + tid;
    const int b = row >> 11;
    const int t = row & (TT-1);

    float cat[D];
    #pragma unroll
    for (int h = 0; h < NH; ++h) {
        const float* ap = attn + ((((size_t)b*NH + h)*TT) + t)*HS;
        #pragma unroll
        for (int e = 0; e < HS; ++e) cat[h*HS+e] = ap[e];
    }

    float y[D];
    const float4* xp = reinterpret_cast<const float4*>(xn + (size_t)row * D);
    #pragma unroll
    for (int i = 0; i < D/4; ++i) {
        float4 t4 = xp[i];
        y[4*i+0]=t4.x; y[4*i+1]=t4.y; y[4*i+2]=t4.z; y[4*i+3]=t4.w;
    }
    #pragma unroll
    for (int d = 0; d < D; ++d) y[d] += bp_s[d];
    for (int c = 0; c < D; ++c) {
        const float cc = cat[c];
        const float* w = &wp_s[c*D];
        #pragma unroll
        for (int d2 = 0; d2 < D; ++d2) y[d2] = fmaf(cc, w[d2], y[d2]);
    }

    // LN2
    float mu = 0.f;
    #pragma unroll
    for (int d = 0; d < D; ++d) mu += y[d];
    mu *= (1.f/D);
    float var = 0.f;
    #pragma unroll
    for (int d = 0; d < D; ++d) { float dd = y[d]-mu; var += dd*dd; }
    var *= (1.f/D);
    const float rs = rsqrtf(var + 1e-5f);
    float y2[D];
    #pragma unroll
    for (int d = 0; d < D; ++d) y2[d] = (y[d]-mu)*rs*g_s[d] + be_s[d];

    // FFN
    float hd[D];
    #pragma unroll
    for (int d = 0; d < D; ++d) hd[d] = b1_s[d];
    for (int c = 0; c < D; ++c) {
        const float cc = y2[c];
        const float* w = &w1_s[c*D];
        #pragma unroll
        for (int d2 = 0; d2 < D; ++d2) hd[d2] = fmaf(cc, w[d2], hd[d2]);
    }
    #pragma unroll
    for (int d = 0; d < D; ++d) hd[d] = fmaxf(hd[d], 0.f);

    float ov[D];
    #pragma unroll
    for (int d = 0; d < D; ++d) ov[d] = y2[d] + b2_s[d];
    for (int c = 0; c < D; ++c) {
        const float cc = hd[c];
        const float* w = &w2_s[c*D];
        #pragma unroll
        for (int d2 = 0; d2 < D; ++d2) ov[d2] = fmaf(cc, w[d2], ov[d2]);
    }

    float4* op = reinterpret_cast<float4*>(out + (size_t)row * D);
    #pragma unroll
    for (int i = 0; i < D/4; ++i) {
        float4 t4; t4.x=ov[4*i+0]; t4.y=ov[4*i+1]; t4.z=ov[4*i+2]; t4.w=ov[4*i+3];
        op[i] = t4;
    }
}

} // namespace

extern "C" void kernel_launch(void* const* d_in, const int* in_sizes, int n_in,
                              void* d_out, int out_size, void* d_ws, size_t ws_size,
                              hipStream_t stream) {
    const float* x   = (const float*)d_in[0];
    const float* Wq  = (const float*)d_in[1];
    const float* Wk  = (const float*)d_in[2];
    const float* Wv  = (const float*)d_in[3];
    const float* Wp  = (const float*)d_in[4];
    const float* bp  = (const float*)d_in[5];
    const float* W1  = (const float*)d_in[6];
    const float* b1  = (const float*)d_in[7];
    const float* W2  = (const float*)d_in[8];
    const float* b2  = (const float*)d_in[9];
    const float* g1  = (const float*)d_in[10];
    const float* be1 = (const float*)d_in[11];
    const float* g2  = (const float*)d_in[12];
    const float* be2 = (const float*)d_in[13];

    const size_t N = (size_t)ROWS * D;   // 1,310,720 elements
    float* xn = (float*)d_ws;
    float* q  = xn + N;
    float* k  = q  + N;
    float* v  = k  + N;
    float* ao = v  + N;

    k_ln_qkv<<<ROWS/128, 128, 0, stream>>>(x, Wq, Wk, Wv, g1, be1, xn, q, k, v);
    k_attn<<<dim3(BB*NH, TT/256), 256, 0, stream>>>(q, k, v, ao);
    k_epilogue<<<ROWS/128, 128, 0, stream>>>(ao, xn, Wp, bp, W1, b1, W2, b2, g2, be2,
                                             (float*)d_out);
}